// Round 1
// baseline (152.699 us; speedup 1.0000x reference)
//
#include <hip/hip_runtime.h>

// ROI max pooling, matching the JAX reference:
//   img:  (1, 200, 200, 512) fp32, NHWC
//   rois: (1, 128, 4) fp32 as (x, y, w, h) in feature-map pixels
//   pool: 7
// out: (1, 128, 7, 7, 512) fp32
//
// Bin boundaries replicate  int(x + k*(w/P))  in strict IEEE fp32
// (separate div/mul/add, no FMA contraction) so the integer pixel ranges
// match the reference exactly; the max over identical pixel sets is then
// bitwise identical.

#define IMG_H 200
#define IMG_W 200
#define IMG_C 512
#define POOL 7
#define NROI 128

__global__ __launch_bounds__(128) void roi_pool_kernel(
    const float* __restrict__ img,
    const float* __restrict__ rois,
    float* __restrict__ out)
{
    const int bin = blockIdx.x % (POOL * POOL);
    const int roi = blockIdx.x / (POOL * POOL);
    const int jy = bin / POOL;
    const int ix = bin % POOL;

    const float rx = rois[roi * 4 + 0];
    const float ry = rois[roi * 4 + 1];
    const float rw = rois[roi * 4 + 2];
    const float rh = rois[roi * 4 + 3];

    // Strict fp32, no contraction: s = w/P; b[k] = int(x + k*s)
    const float sx = __fdiv_rn(rw, 7.0f);
    const float sy = __fdiv_rn(rh, 7.0f);
    const int x1 = (int)__fadd_rn(rx, __fmul_rn((float)ix,       sx));
    const int x2 = (int)__fadd_rn(rx, __fmul_rn((float)(ix + 1), sx));
    const int y1 = (int)__fadd_rn(ry, __fmul_rn((float)jy,       sy));
    const int y2 = (int)__fadd_rn(ry, __fmul_rn((float)(jy + 1), sy));

    const int c4 = threadIdx.x;            // 0..127, one float4 of channels
    const float4* __restrict__ img4 = (const float4*)img;

    float4 m = make_float4(-INFINITY, -INFINITY, -INFINITY, -INFINITY);
    for (int y = y1; y < y2; ++y) {
        const float4* __restrict__ row = img4 + ((size_t)y * IMG_W) * (IMG_C / 4) + c4;
        for (int x = x1; x < x2; ++x) {
            float4 v = row[(size_t)x * (IMG_C / 4)];
            m.x = fmaxf(m.x, v.x);
            m.y = fmaxf(m.y, v.y);
            m.z = fmaxf(m.z, v.z);
            m.w = fmaxf(m.w, v.w);
        }
    }

    float4* __restrict__ out4 = (float4*)out;
    out4[((size_t)(roi * POOL + jy) * POOL + ix) * (IMG_C / 4) + c4] = m;
}

extern "C" void kernel_launch(void* const* d_in, const int* in_sizes, int n_in,
                              void* d_out, int out_size, void* d_ws, size_t ws_size,
                              hipStream_t stream) {
    (void)in_sizes; (void)n_in; (void)d_ws; (void)ws_size; (void)out_size;
    const float* img  = (const float*)d_in[0];
    const float* rois = (const float*)d_in[1];
    // d_in[2] is pool_size (=7), hardcoded.
    float* out = (float*)d_out;

    dim3 grid(NROI * POOL * POOL);
    dim3 block(128);
    roi_pool_kernel<<<grid, block, 0, stream>>>(img, rois, out);
}

// Round 2
// 142.848 us; speedup vs baseline: 1.0690x; 1.0690x over previous
//
#include <hip/hip_runtime.h>

// ROI max pooling, matching the JAX reference:
//   img:  (1, 200, 200, 512) fp32, NHWC
//   rois: (1, 128, 4) fp32 as (x, y, w, h) in feature-map pixels
//   pool: 7
// out: (1, 128, 7, 7, 512) fp32
//
// Bin boundaries replicate  int(x + k*(w/P))  in strict IEEE fp32
// (separate div/mul/add, no FMA contraction) so the integer pixel ranges
// match the reference exactly; the max over identical pixel sets is then
// bitwise identical.
//
// R2: latency-bound fix — process two rows concurrently (independent
// accumulator chains) + 4x unrolled x-loop for ~8 loads in flight/thread.

#define IMG_H 200
#define IMG_W 200
#define IMG_C 512
#define C4 (IMG_C / 4)   // 128 float4 slots per pixel
#define POOL 7
#define NROI 128

__device__ __forceinline__ float4 max4(float4 a, float4 b) {
    return make_float4(fmaxf(a.x, b.x), fmaxf(a.y, b.y),
                       fmaxf(a.z, b.z), fmaxf(a.w, b.w));
}

__global__ __launch_bounds__(128) void roi_pool_kernel(
    const float* __restrict__ img,
    const float* __restrict__ rois,
    float* __restrict__ out)
{
    const int bin = blockIdx.x % (POOL * POOL);
    const int roi = blockIdx.x / (POOL * POOL);
    const int jy = bin / POOL;
    const int ix = bin % POOL;

    const float rx = rois[roi * 4 + 0];
    const float ry = rois[roi * 4 + 1];
    const float rw = rois[roi * 4 + 2];
    const float rh = rois[roi * 4 + 3];

    // Strict fp32, no contraction: s = w/P; b[k] = int(x + k*s)
    const float sx = __fdiv_rn(rw, 7.0f);
    const float sy = __fdiv_rn(rh, 7.0f);
    const int x1 = (int)__fadd_rn(rx, __fmul_rn((float)ix,       sx));
    const int x2 = (int)__fadd_rn(rx, __fmul_rn((float)(ix + 1), sx));
    const int y1 = (int)__fadd_rn(ry, __fmul_rn((float)jy,       sy));
    const int y2 = (int)__fadd_rn(ry, __fmul_rn((float)(jy + 1), sy));

    const int c4 = threadIdx.x;            // 0..127, one float4 of channels
    const float4* __restrict__ img4 = (const float4*)img;

    float4 m0 = make_float4(-INFINITY, -INFINITY, -INFINITY, -INFINITY);
    float4 m1 = m0;

    int y = y1;
    // Two rows at a time: independent load+max chains double MLP.
    for (; y + 2 <= y2; y += 2) {
        const float4* __restrict__ rowA = img4 + ((size_t)y       * IMG_W) * C4 + c4;
        const float4* __restrict__ rowB = img4 + ((size_t)(y + 1) * IMG_W) * C4 + c4;
        #pragma unroll 4
        for (int x = x1; x < x2; ++x) {
            float4 a = rowA[(size_t)x * C4];
            float4 b = rowB[(size_t)x * C4];
            m0 = max4(m0, a);
            m1 = max4(m1, b);
        }
    }
    if (y < y2) {
        const float4* __restrict__ rowA = img4 + ((size_t)y * IMG_W) * C4 + c4;
        #pragma unroll 4
        for (int x = x1; x < x2; ++x) {
            float4 a = rowA[(size_t)x * C4];
            m0 = max4(m0, a);
        }
    }
    float4 m = max4(m0, m1);

    float4* __restrict__ out4 = (float4*)out;
    out4[((size_t)(roi * POOL + jy) * POOL + ix) * C4 + c4] = m;
}

extern "C" void kernel_launch(void* const* d_in, const int* in_sizes, int n_in,
                              void* d_out, int out_size, void* d_ws, size_t ws_size,
                              hipStream_t stream) {
    (void)in_sizes; (void)n_in; (void)d_ws; (void)ws_size; (void)out_size;
    const float* img  = (const float*)d_in[0];
    const float* rois = (const float*)d_in[1];
    // d_in[2] is pool_size (=7), hardcoded.
    float* out = (float*)d_out;

    dim3 grid(NROI * POOL * POOL);
    dim3 block(128);
    roi_pool_kernel<<<grid, block, 0, stream>>>(img, rois, out);
}